// Round 1
// baseline (585.827 us; speedup 1.0000x reference)
//
#include <hip/hip_runtime.h>
#include <hip/hip_bf16.h>
#include <math.h>

#define DEMB 64      // embedding dim
#define BK   16      // k-chunk
#define BM   32      // rows per block
#define KSPLIT 4     // k-split groups
#define LDSP 76      // LDS row stride in floats (16B-aligned: 76*4=304)

// Partial GEMM: part[kg][row][c] = sum over chunks c≡kg (mod 4) of X[row][k]*W[k][c]
// X: [nrows][Din] row-major, W: [Din][64] row-major.
__global__ __launch_bounds__(256) void gemm_part(
    const float* __restrict__ X, const float* __restrict__ W,
    float* __restrict__ part, int nrows, int part_rows, int Din)
{
    __shared__ float At[BK][LDSP];  // A transposed: At[kk][m]
    __shared__ float Bs[BK][LDSP];  // Bs[kk][c]

    const int tid = threadIdx.x;
    const int r0  = blockIdx.x * BM;
    const int kg  = blockIdx.y;

    const int tx = tid & 15;        // cols 4*tx..4*tx+3
    const int ty = tid >> 4;        // rows 2*ty..2*ty+1

    // A-tile load mapping: 32 rows x 16 k, float2 per thread
    const int arow = tid >> 3;      // 0..31
    const int akq  = tid & 7;       // k offset 2*akq
    // B-tile load mapping: 16 k x 64 c, float4 per thread
    const int bk = tid >> 4;        // 0..15
    const int bc = tid & 15;        // cols 4*bc

    float acc[2][4];
    #pragma unroll
    for (int i = 0; i < 2; ++i)
        #pragma unroll
        for (int j = 0; j < 4; ++j) acc[i][j] = 0.f;

    const int nchunk = Din / BK;
    const bool aval = (r0 + arow) < nrows;
    const float* aptr = X + (size_t)(r0 + arow) * Din;

    for (int c = kg; c < nchunk; c += KSPLIT) {
        const int k0 = c * BK;
        float2 a2 = make_float2(0.f, 0.f);
        if (aval) a2 = *reinterpret_cast<const float2*>(aptr + k0 + 2 * akq);
        float4 b4 = *reinterpret_cast<const float4*>(W + (size_t)(k0 + bk) * DEMB + 4 * bc);

        __syncthreads();   // previous iteration's LDS reads done
        At[2 * akq + 0][arow] = a2.x;
        At[2 * akq + 1][arow] = a2.y;
        *reinterpret_cast<float4*>(&Bs[bk][4 * bc]) = b4;
        __syncthreads();

        #pragma unroll
        for (int kk = 0; kk < BK; ++kk) {
            float2 a = *reinterpret_cast<const float2*>(&At[kk][2 * ty]);
            float4 b = *reinterpret_cast<const float4*>(&Bs[kk][4 * tx]);
            acc[0][0] += a.x * b.x; acc[0][1] += a.x * b.y;
            acc[0][2] += a.x * b.z; acc[0][3] += a.x * b.w;
            acc[1][0] += a.y * b.x; acc[1][1] += a.y * b.y;
            acc[1][2] += a.y * b.z; acc[1][3] += a.y * b.w;
        }
    }

    float* pout = part + (size_t)kg * part_rows * DEMB;
    #pragma unroll
    for (int i = 0; i < 2; ++i) {
        int row = r0 + 2 * ty + i;
        if (row < nrows) {
            float4 v = make_float4(acc[i][0], acc[i][1], acc[i][2], acc[i][3]);
            *reinterpret_cast<float4*>(pout + (size_t)row * DEMB + 4 * tx) = v;
        }
    }
}

// Reduce support partials + bias, L2-normalize -> sn [S][64]
__global__ void support_finalize(const float* __restrict__ spart,
                                 const float* __restrict__ bias,
                                 float* __restrict__ sn, int S, int part_rows)
{
    int s = blockIdx.x;
    int c = threadIdx.x;  // 64 threads
    float e = bias[c];
    #pragma unroll
    for (int g = 0; g < KSPLIT; ++g)
        e += spart[(size_t)g * part_rows * DEMB + (size_t)s * DEMB + c];
    float ss = e * e;
    #pragma unroll
    for (int o = 32; o >= 1; o >>= 1) ss += __shfl_xor(ss, o, 64);
    float n = fmaxf(sqrtf(ss), 1e-8f);
    sn[(size_t)s * DEMB + c] = e / n;
}

// Fused: query reduce+bias+normalize, cosine sims vs 100 supports,
// softmax over supports, one-hot bin accumulation. One wave per query.
__global__ __launch_bounds__(256) void attend(
    const float* __restrict__ qpart, const float* __restrict__ sn_g,
    const float* __restrict__ bias, const int* __restrict__ labels,
    const int* __restrict__ p_nway, float* __restrict__ out,
    int S, int qstride)
{
    __shared__ float sn[100][65];
    __shared__ float qn[4][64];
    __shared__ float bins[4][32];
    __shared__ int   lab[100];

    const int tid  = threadIdx.x;
    const int w    = tid >> 6;
    const int lane = tid & 63;
    const int nw   = *p_nway;

    for (int i = tid; i < S * DEMB; i += 256) sn[i >> 6][i & 63] = sn_g[i];
    if (tid < S) lab[tid] = labels[tid];

    const int q = blockIdx.x * 4 + w;

    // query embedding: reduce K-split partials + bias, normalize
    float e = bias[lane];
    #pragma unroll
    for (int g = 0; g < KSPLIT; ++g)
        e += qpart[(size_t)g * qstride * DEMB + (size_t)q * DEMB + lane];
    float ss = e * e;
    #pragma unroll
    for (int o = 32; o >= 1; o >>= 1) ss += __shfl_xor(ss, o, 64);
    e /= fmaxf(sqrtf(ss), 1e-8f);
    qn[w][lane] = e;
    if (lane < 32) bins[w][lane] = 0.f;
    __syncthreads();

    // sims for supports s0=lane, s1=lane+64
    const bool v1 = (lane + 64) < S;
    const int  s1 = v1 ? lane + 64 : 0;
    float sim0 = 0.f, sim1 = 0.f;
    #pragma unroll 8
    for (int c = 0; c < DEMB; ++c) {
        float qc = qn[w][c];
        sim0 += qc * sn[lane][c];
        sim1 += qc * sn[s1][c];
    }
    if (!v1) sim1 = -INFINITY;

    float lm = fmaxf(sim0, sim1);
    #pragma unroll
    for (int o = 32; o >= 1; o >>= 1) lm = fmaxf(lm, __shfl_xor(lm, o, 64));
    float e0 = __expf(sim0 - lm);
    float e1 = v1 ? __expf(sim1 - lm) : 0.f;
    float d = e0 + e1;
    #pragma unroll
    for (int o = 32; o >= 1; o >>= 1) d += __shfl_xor(d, o, 64);

    atomicAdd(&bins[w][lab[lane]], e0);
    if (v1) atomicAdd(&bins[w][lab[s1]], e1);
    __syncthreads();

    if (lane < nw) out[(size_t)q * nw + lane] = bins[w][lane] / d;
}

extern "C" void kernel_launch(void* const* d_in, const int* in_sizes, int n_in,
                              void* d_out, int out_size, void* d_ws, size_t ws_size,
                              hipStream_t stream)
{
    const float* sup    = (const float*)d_in[0];
    const int*   labels = (const int*)d_in[1];
    const float* qry    = (const float*)d_in[2];
    const int*   p_nway = (const int*)d_in[3];
    const float* W      = (const float*)d_in[5];
    const float* bias   = (const float*)d_in[6];
    float* out = (float*)d_out;

    const int S   = in_sizes[1];          // 100
    const int D   = in_sizes[6];          // 64
    const int Din = in_sizes[5] / D;      // 21168
    const int Q   = in_sizes[2] / Din;    // 4096

    float* ws = (float*)d_ws;
    const int spart_rows = ((S + BM - 1) / BM) * BM;          // 128
    float* qpart = ws;                                         // [4][Q][64]
    float* spart = qpart + (size_t)KSPLIT * Q * D;             // [4][128][64]
    float* sn    = spart + (size_t)KSPLIT * spart_rows * D;    // [S][64]

    dim3 g2q(Q / BM, KSPLIT);
    hipLaunchKernelGGL(gemm_part, g2q, dim3(256), 0, stream, qry, W, qpart, Q, Q, Din);
    dim3 g2s((S + BM - 1) / BM, KSPLIT);
    hipLaunchKernelGGL(gemm_part, g2s, dim3(256), 0, stream, sup, W, spart, S, spart_rows, Din);
    hipLaunchKernelGGL(support_finalize, dim3(S), dim3(64), 0, stream, spart, bias, sn, S, spart_rows);
    hipLaunchKernelGGL(attend, dim3(Q / 4), dim3(256), 0, stream, qpart, sn, bias, labels, p_nway, out, S, Q);
}

// Round 2
// 137.565 us; speedup vs baseline: 4.2586x; 4.2586x over previous
//
#include <hip/hip_runtime.h>
#include <hip/hip_bf16.h>
#include <math.h>

#define DEMB 64
#define BM   64
#define KSMAX 16

using short8 = __attribute__((ext_vector_type(8))) short;
using u16x8  = __attribute__((ext_vector_type(8))) unsigned short;
using f32x4  = __attribute__((ext_vector_type(4))) float;

__device__ __forceinline__ unsigned short f2bf(float x) {
    union { float f; unsigned u; } v; v.f = x;
    unsigned r = v.u + 0x7fffu + ((v.u >> 16) & 1u);   // RNE
    return (unsigned short)(r >> 16);
}

// W [Din][64] fp32 -> Wt [64][Wstride] bf16 (transposed, K zero-padded)
__global__ __launch_bounds__(256) void prep_wt(
    const float* __restrict__ W, unsigned short* __restrict__ Wt,
    int Din, int Wstride)
{
    __shared__ unsigned short tile[64][65];
    const int k0 = blockIdx.x * 64;
    const int tid = threadIdx.x;
    #pragma unroll
    for (int i = 0; i < 16; ++i) {
        int kk = i * 4 + (tid >> 6);
        int c  = tid & 63;
        int k  = k0 + kk;
        float x = (k < Din) ? W[(size_t)k * DEMB + c] : 0.f;
        tile[kk][c] = f2bf(x);
    }
    __syncthreads();
    #pragma unroll
    for (int i = 0; i < 16; ++i) {
        int c  = i * 4 + (tid >> 6);
        int kk = tid & 63;
        Wt[(size_t)c * Wstride + k0 + kk] = tile[kk][c];
    }
}

// MFMA GEMM: rows of Xq (and Xs for bx>=nQb) times Wt -> K-split fp32 partials.
__global__ __launch_bounds__(256) void gemm_mfma(
    const float* __restrict__ Xq, const float* __restrict__ Xs,
    const unsigned short* __restrict__ Wt,
    float* __restrict__ qpart, float* __restrict__ spart,
    int Q, int S, int Din, int Wstride, int nQb, int ks)
{
    __shared__ unsigned short As[2][BM * 32];
    __shared__ unsigned short Ws[2][64 * 32];

    const int tid  = threadIdx.x;
    const int wave = tid >> 6;
    const int lane = tid & 63;
    const int kg   = blockIdx.y;

    const bool isS = (int)blockIdx.x >= nQb;
    const float* X = isS ? Xs : Xq;
    const int nrows = isS ? S : Q;
    const int r0 = (isS ? ((int)blockIdx.x - nQb) : (int)blockIdx.x) * BM;
    float* part = isS ? spart : qpart;
    const int prow = isS ? 128 : Q;

    // A staging map: thread -> row=tid>>2, k-offset=(tid&3)*8 (8 floats)
    const int arow = tid >> 2;
    const int ak   = (tid & 3) * 8;
    const bool aval = (r0 + arow) < nrows;
    const float* aptr = X + (size_t)(r0 + arow) * Din;

    // B staging map: thread -> col=tid>>2, k-offset=(tid&3)*8 (8 bf16 = 16B)
    const unsigned short* wptr = Wt + (size_t)(tid >> 2) * Wstride + (tid & 3) * 8;

    // fragment read coords
    const int frow = 16 * wave + (lane & 15);
    const int fk   = (lane >> 4) * 8;

    f32x4 acc[4] = { {0.f,0.f,0.f,0.f}, {0.f,0.f,0.f,0.f},
                     {0.f,0.f,0.f,0.f}, {0.f,0.f,0.f,0.f} };

    const int nchunk = (Din + 31) >> 5;

    // prologue: stage chunk kg into buffer 0
    {
        const int k0 = kg * 32;
        float4 a0 = {}, a1 = {};
        const int kk = k0 + ak;
        if (aval && kk + 8 <= Din) {         // Din % 8 == 0
            a0 = *reinterpret_cast<const float4*>(aptr + kk);
            a1 = *reinterpret_cast<const float4*>(aptr + kk + 4);
        }
        u16x8 wv = *reinterpret_cast<const u16x8*>(wptr + k0);
        u16x8 ap = { f2bf(a0.x), f2bf(a0.y), f2bf(a0.z), f2bf(a0.w),
                     f2bf(a1.x), f2bf(a1.y), f2bf(a1.z), f2bf(a1.w) };
        *reinterpret_cast<u16x8*>(&As[0][arow * 32 + ak]) = ap;
        *reinterpret_cast<u16x8*>(&Ws[0][tid * 8]) = wv;
        __syncthreads();
    }

    int cur = 0;
    for (int c = kg; c < nchunk; c += ks) {
        const int cn = c + ks;
        const bool pf = (cn < nchunk);
        float4 a0 = {}, a1 = {};
        u16x8 wv = {0,0,0,0,0,0,0,0};
        if (pf) {
            const int k0 = cn * 32;
            const int kk = k0 + ak;
            if (aval && kk + 8 <= Din) {
                a0 = *reinterpret_cast<const float4*>(aptr + kk);
                a1 = *reinterpret_cast<const float4*>(aptr + kk + 4);
            }
            wv = *reinterpret_cast<const u16x8*>(wptr + k0);
        }

        short8 af = *reinterpret_cast<const short8*>(&As[cur][frow * 32 + fk]);
        #pragma unroll
        for (int cb = 0; cb < 4; ++cb) {
            short8 bf = *reinterpret_cast<const short8*>(
                &Ws[cur][(16 * cb + (lane & 15)) * 32 + fk]);
            acc[cb] = __builtin_amdgcn_mfma_f32_16x16x32_bf16(af, bf, acc[cb], 0, 0, 0);
        }

        if (pf) {
            u16x8 ap = { f2bf(a0.x), f2bf(a0.y), f2bf(a0.z), f2bf(a0.w),
                         f2bf(a1.x), f2bf(a1.y), f2bf(a1.z), f2bf(a1.w) };
            *reinterpret_cast<u16x8*>(&As[cur ^ 1][arow * 32 + ak]) = ap;
            *reinterpret_cast<u16x8*>(&Ws[cur ^ 1][tid * 8]) = wv;
        }
        __syncthreads();
        cur ^= 1;
    }

    // epilogue: C layout col=lane&15, row=(lane>>4)*4+i
    #pragma unroll
    for (int cb = 0; cb < 4; ++cb) {
        #pragma unroll
        for (int i = 0; i < 4; ++i) {
            int row = r0 + 16 * wave + (lane >> 4) * 4 + i;
            if (row < nrows)
                part[((size_t)kg * prow + row) * DEMB + 16 * cb + (lane & 15)] = acc[cb][i];
        }
    }
}

// Reduce support partials + bias, L2-normalize -> sn [S][64]
__global__ void support_finalize(const float* __restrict__ spart,
                                 const float* __restrict__ bias,
                                 float* __restrict__ sn, int S, int ks)
{
    int s = blockIdx.x;
    int c = threadIdx.x;  // 64
    float e = bias[c];
    for (int g = 0; g < ks; ++g)
        e += spart[((size_t)g * 128 + s) * DEMB + c];
    float ss = e * e;
    #pragma unroll
    for (int o = 32; o >= 1; o >>= 1) ss += __shfl_xor(ss, o, 64);
    sn[(size_t)s * DEMB + c] = e / fmaxf(sqrtf(ss), 1e-8f);
}

// Fused: query reduce+bias+normalize, cosine sims, softmax, one-hot bins.
__global__ __launch_bounds__(256) void attend(
    const float* __restrict__ qpart, const float* __restrict__ sn_g,
    const float* __restrict__ bias, const int* __restrict__ labels,
    const int* __restrict__ p_nway, float* __restrict__ out,
    int S, int Q, int ks)
{
    __shared__ float sn[100][65];
    __shared__ float qn[4][64];
    __shared__ float bins[4][32];
    __shared__ int   lab[100];

    const int tid  = threadIdx.x;
    const int w    = tid >> 6;
    const int lane = tid & 63;
    const int nw   = *p_nway;

    for (int i = tid; i < S * DEMB; i += 256) sn[i >> 6][i & 63] = sn_g[i];
    if (tid < S) lab[tid] = labels[tid];

    const int q = blockIdx.x * 4 + w;

    float e = bias[lane];
    for (int g = 0; g < ks; ++g)
        e += qpart[((size_t)g * Q + q) * DEMB + lane];
    float ss = e * e;
    #pragma unroll
    for (int o = 32; o >= 1; o >>= 1) ss += __shfl_xor(ss, o, 64);
    e /= fmaxf(sqrtf(ss), 1e-8f);
    qn[w][lane] = e;
    if (lane < 32) bins[w][lane] = 0.f;
    __syncthreads();

    const bool v1 = (lane + 64) < S;
    const int  s1 = v1 ? lane + 64 : 0;
    float sim0 = 0.f, sim1 = 0.f;
    #pragma unroll 8
    for (int c = 0; c < DEMB; ++c) {
        float qc = qn[w][c];
        sim0 += qc * sn[lane][c];
        sim1 += qc * sn[s1][c];
    }
    if (!v1) sim1 = -INFINITY;

    float lm = fmaxf(sim0, sim1);
    #pragma unroll
    for (int o = 32; o >= 1; o >>= 1) lm = fmaxf(lm, __shfl_xor(lm, o, 64));
    float e0 = __expf(sim0 - lm);
    float e1 = v1 ? __expf(sim1 - lm) : 0.f;
    float d = e0 + e1;
    #pragma unroll
    for (int o = 32; o >= 1; o >>= 1) d += __shfl_xor(d, o, 64);

    atomicAdd(&bins[w][lab[lane]], e0);
    if (v1) atomicAdd(&bins[w][lab[s1]], e1);
    __syncthreads();

    if (lane < nw) out[(size_t)q * nw + lane] = bins[w][lane] / d;
}

extern "C" void kernel_launch(void* const* d_in, const int* in_sizes, int n_in,
                              void* d_out, int out_size, void* d_ws, size_t ws_size,
                              hipStream_t stream)
{
    const float* sup    = (const float*)d_in[0];
    const int*   labels = (const int*)d_in[1];
    const float* qry    = (const float*)d_in[2];
    const int*   p_nway = (const int*)d_in[3];
    const float* W      = (const float*)d_in[5];
    const float* bias   = (const float*)d_in[6];
    float* out = (float*)d_out;

    const int D   = DEMB;                 // 64
    const int Din = in_sizes[5] / D;      // 21168
    const int Q   = in_sizes[2] / Din;    // 4096
    const int S   = in_sizes[1];          // 100

    const int nchunk  = (Din + 31) / 32;  // 662
    const int Wstride = nchunk * 32;      // 21184

    // workspace layout
    char* wsb = (char*)d_ws;
    size_t wt_bytes = (size_t)64 * Wstride * sizeof(unsigned short); // 2.71 MB
    wt_bytes = (wt_bytes + 255) & ~(size_t)255;
    size_t sn_bytes = (size_t)S * D * sizeof(float);
    sn_bytes = (sn_bytes + 255) & ~(size_t)255;
    size_t per_ks = ((size_t)Q * D + 128 * D) * sizeof(float);

    size_t fixed = wt_bytes + sn_bytes;
    int ks = 1;
    if (ws_size > fixed + per_ks) {
        size_t avail = (ws_size - fixed) / per_ks;
        ks = (int)(avail < KSMAX ? avail : KSMAX);
        if (ks < 1) ks = 1;
    }

    unsigned short* Wt = (unsigned short*)wsb;
    float* sn    = (float*)(wsb + wt_bytes);
    float* spart = (float*)(wsb + wt_bytes + sn_bytes);
    float* qpart = spart + (size_t)ks * 128 * D;

    hipLaunchKernelGGL(prep_wt, dim3((Din + 63) / 64), dim3(256), 0, stream,
                       W, Wt, Din, Wstride);

    const int nQb = (Q + BM - 1) / BM;          // 64
    const int nSb = (S + BM - 1) / BM;          // 2
    hipLaunchKernelGGL(gemm_mfma, dim3(nQb + nSb, ks), dim3(256), 0, stream,
                       qry, sup, Wt, qpart, spart, Q, S, Din, Wstride, nQb, ks);

    hipLaunchKernelGGL(support_finalize, dim3(S), dim3(64), 0, stream,
                       spart, bias, sn, S, ks);

    hipLaunchKernelGGL(attend, dim3(Q / 4), dim3(256), 0, stream,
                       qpart, sn, bias, labels, p_nway, out, S, Q, ks);
}